// Round 10
// baseline (163.342 us; speedup 1.0000x reference)
//
#include <hip/hip_runtime.h>
#include <cstdint>
#include <cstddef>

// ---------------- types / helpers ----------------
typedef __attribute__((ext_vector_type(8))) __bf16 bf16x8;
typedef __attribute__((ext_vector_type(4))) float  f32x4;

#define MFMA16(a, b, c) __builtin_amdgcn_mfma_f32_16x16x32_bf16((a), (b), (c), 0, 0, 0)

#define T_SEQ 4096
#define NHEADS 8
#define DH 64
#define NROWS (2 * NHEADS * T_SEQ)   // 65536 total (bh, q) rows
#define NEG_INF (-__builtin_huge_valf())
// 1/sqrt(64) * log2(e)  (softmax done in exp2 domain)
#define SCALE_Q 0.18033688011112042f

__device__ __forceinline__ unsigned short f2bf(float f) {
  unsigned int u = __float_as_uint(f);
  u += 0x7fffu + ((u >> 16) & 1u);
  return (unsigned short)(u >> 16);
}

// pack two f32 -> two bf16 in one u32 (round-half-up; a = low half)
__device__ __forceinline__ unsigned int pack_bf2(float a, float b) {
  unsigned int au = __float_as_uint(a) + 0x8000u;
  unsigned int bu = __float_as_uint(b) + 0x8000u;
  return (au >> 16) | (bu & 0xffff0000u);
}

// async global->LDS, 16B per lane. LDS dest = uniform base + lane*16.
__device__ __forceinline__ void gload16(const unsigned short* g, unsigned short* l) {
  __builtin_amdgcn_global_load_lds(
      (const __attribute__((address_space(1))) unsigned short*)g,
      (__attribute__((address_space(3))) unsigned short*)l, 16, 0, 0);
}

// ---------------- conversion kernels ----------------
__global__ void cvt_x_kernel(const float* __restrict__ x,
                             unsigned short* __restrict__ xb, int n4) {
  int i = blockIdx.x * blockDim.x + threadIdx.x;
  if (i >= n4) return;
  float4 v = ((const float4*)x)[i];
  ushort4 o;
  o.x = f2bf(v.x); o.y = f2bf(v.y); o.z = f2bf(v.z); o.w = f2bf(v.w);
  ((ushort4*)xb)[i] = o;
}

// w [512][N] (K=512 rows) -> wT [N][512] bf16
__global__ void cvt_T_kernel(const float* __restrict__ w,
                             unsigned short* __restrict__ wT, int N, int total) {
  int i = blockIdx.x * blockDim.x + threadIdx.x;
  if (i >= total) return;
  int n = i >> 9, k = i & 511;
  wT[i] = f2bf(w[(size_t)k * N + n]);
}

// ---------------- GEMM: C = A[M,K] * BT[N,K]^T + bias ----------------
// 128x128 block tile, BK=32, 4 waves (each a 64x64 quadrant), 16x16x32 MFMA.
// EPI==0: QKV epilogue (q/k -> [B*H][T][64], V -> transposed [B*H][64][T])
// EPI==1: fp32 output [M][512] with bias
template <int EPI>
__global__ __launch_bounds__(256) void gemm_bt(
    const unsigned short* __restrict__ A,
    const unsigned short* __restrict__ BT,
    const float* __restrict__ bias,
    float* __restrict__ outf,
    unsigned short* __restrict__ oq,
    unsigned short* __restrict__ ok,
    unsigned short* __restrict__ ovT,
    int K) {
  __shared__ alignas(16) unsigned short As[128 * 32];
  __shared__ alignas(16) unsigned short Bs[128 * 32];

  const int t = threadIdx.x;
  const int lane = t & 63;
  const int w = t >> 6;
  const int wr = (w >> 1) * 64;
  const int wc = (w & 1) * 64;
  const int g = lane >> 4, c = lane & 15;
  const int row0 = blockIdx.y * 128, col0 = blockIdx.x * 128;

  const int crow = t >> 2;          // 0..63
  const int ccol = (t & 3) * 8;     // 0,8,16,24
  const unsigned short* Ag0 = A + (size_t)(row0 + crow) * K + ccol;
  const unsigned short* Ag1 = A + (size_t)(row0 + 64 + crow) * K + ccol;
  const unsigned short* Bg0 = BT + (size_t)(col0 + crow) * K + ccol;
  const unsigned short* Bg1 = BT + (size_t)(col0 + 64 + crow) * K + ccol;

  f32x4 acc[4][4] = {};

  for (int k0 = 0; k0 < K; k0 += 32) {
    int4 a0 = *(const int4*)(Ag0 + k0);
    int4 a1 = *(const int4*)(Ag1 + k0);
    int4 b0 = *(const int4*)(Bg0 + k0);
    int4 b1 = *(const int4*)(Bg1 + k0);
    __syncthreads();
    *(int4*)&As[crow * 32 + ccol] = a0;
    *(int4*)&As[(64 + crow) * 32 + ccol] = a1;
    *(int4*)&Bs[crow * 32 + ccol] = b0;
    *(int4*)&Bs[(64 + crow) * 32 + ccol] = b1;
    __syncthreads();

    bf16x8 af[4], bfr[4];
#pragma unroll
    for (int m = 0; m < 4; ++m)
      af[m] = *(const bf16x8*)&As[(wr + m * 16 + c) * 32 + g * 8];
#pragma unroll
    for (int n = 0; n < 4; ++n)
      bfr[n] = *(const bf16x8*)&Bs[(wc + n * 16 + c) * 32 + g * 8];
#pragma unroll
    for (int m = 0; m < 4; ++m)
#pragma unroll
      for (int n = 0; n < 4; ++n)
        acc[m][n] = MFMA16(af[m], bfr[n], acc[m][n]);
  }

  // epilogue. D layout: row = g*4 + i, col = c (verified m89/m91 mapping)
#pragma unroll
  for (int m = 0; m < 4; ++m) {
#pragma unroll
    for (int n = 0; n < 4; ++n) {
      const int col = col0 + wc + n * 16 + c;
      const float bv = bias[col];
      if constexpr (EPI == 0) {
        const int which = col >> 9;          // wave-uniform (depends on block,n)
        const int h = (col >> 6) & 7;
        const int dh = col & 63;
        const int r0 = row0 + wr + m * 16 + g * 4;
        const int bb = r0 >> 12;             // r0 / T_SEQ (4 rows never cross)
        const int tt0 = r0 & 4095;
        if (which == 2) {
          // V transposed: vT[(bb*H + h)*64 + dh][tt0..tt0+3] -- contiguous
          ushort4 pk;
          pk.x = f2bf(acc[m][n][0] + bv);
          pk.y = f2bf(acc[m][n][1] + bv);
          pk.z = f2bf(acc[m][n][2] + bv);
          pk.w = f2bf(acc[m][n][3] + bv);
          *(ushort4*)&ovT[((size_t)((bb * NHEADS + h) * DH + dh)) * T_SEQ + tt0] = pk;
        } else {
          unsigned short* dst = (which == 0) ? oq : ok;
          const float sc = (which == 0) ? SCALE_Q : 1.0f;
#pragma unroll
          for (int i = 0; i < 4; ++i) {
            const size_t idx =
                ((size_t)((bb * NHEADS + h) * T_SEQ + tt0 + i)) * DH + dh;
            dst[idx] = f2bf((acc[m][n][i] + bv) * sc);
          }
        }
      } else {
#pragma unroll
        for (int i = 0; i < 4; ++i) {
          const int row = row0 + wr + m * 16 + g * 4 + i;
          outf[(size_t)row * 512 + col] = acc[m][n][i] + bv;
        }
      }
    }
  }
}

// ---------------- flash attention (causal, split-K, 2 q-sub-tiles/wave) ----
// grid (B*H, 16, 2). Block (bh, y, hv) runs two passes over q-SUPERBLOCKS of
// 128 rows: sb = y and sb = 31-y; split-K half hv of each. Each wave owns TWO
// 16-row q-sub-tiles (qw, qw+64) so the K/V LDS fragments (wave-invariant in
// the swapped layout) are read ONCE per tile and feed 2x the MFMA work --
// K/V LDS reads and staging per q-row are HALVED vs round 9. Sub-tile A
// skips tiles fully behind its diagonal (block-uniform). Every block does
// ~34 tiles; 512 equal blocks, 2/CU resident. Swapped QK^T / defer-max /
// XOR-swizzle / split-K merge as before.
__global__ __launch_bounds__(256) void attn_kernel(
    const unsigned short* __restrict__ qb,
    const unsigned short* __restrict__ kb,
    const unsigned short* __restrict__ vtb,
    unsigned short* __restrict__ ob0,
    unsigned short* __restrict__ ob1,
    float* __restrict__ sb) {
  const int bh = blockIdx.x;
  const int y = blockIdx.y;
  const int hv = blockIdx.z;
  const int w = threadIdx.x >> 6;
  const int lane = threadIdx.x & 63;
  const int g = lane >> 4, c = lane & 15;

  // K tile: rows = key (64), cols = d (64, 128B). V tile: rows = d, cols = t.
  __shared__ alignas(16) unsigned short Ks[2][64 * 64];
  __shared__ alignas(16) unsigned short Vs[2][64 * 64];
  __shared__ alignas(16) unsigned short Plds[4][16 * 64];

  const unsigned short* Qp  = qb + (size_t)bh * T_SEQ * DH;
  const unsigned short* Kp  = kb + (size_t)bh * T_SEQ * DH;
  const unsigned short* VTp = vtb + (size_t)bh * DH * T_SEQ;

  unsigned short* obh = hv ? ob1 : ob0;
  float* sbh = sb + (size_t)hv * NROWS + (size_t)bh * T_SEQ;

  // staging: wave w stages LDS rows 16w..16w+15 of both tiles (2 gloads each).
  // source column pre-swizzled: row r keeps byte-col cb at cb ^ ((r&7)<<4);
  // gload instr writes rows q*8+l8 linearly, so swizzle = 8*(lc ^ l8) elems.
  const int l8 = lane >> 3, lc = lane & 7;
  const int swzE = 8 * (lc ^ l8);
  const unsigned short* Ksrc0 = Kp + (size_t)(16 * w + l8) * DH + swzE;
  const unsigned short* Ksrc1 = Kp + (size_t)(16 * w + 8 + l8) * DH + swzE;
  const unsigned short* Vsrc0 = VTp + (size_t)(16 * w + l8) * T_SEQ + swzE;
  const unsigned short* Vsrc1 = VTp + (size_t)(16 * w + 8 + l8) * T_SEQ + swzE;

#define STAGE(B, J0) do {                                              \
    gload16(Ksrc0 + (size_t)(J0) * DH, &Ks[B][(2 * w) * 512]);         \
    gload16(Ksrc1 + (size_t)(J0) * DH, &Ks[B][(2 * w + 1) * 512]);     \
    gload16(Vsrc0 + (J0), &Vs[B][(2 * w) * 512]);                      \
    gload16(Vsrc1 + (J0), &Vs[B][(2 * w + 1) * 512]);                  \
  } while (0)

  const int swb = (c & 7) << 4;  // read-side xor (bytes)
  char* Pw = (char*)&Plds[w][0];

  for (int pass = 0; pass < 2; ++pass) {
    const int sbk = pass ? (31 - y) : y;      // q-superblock (128 rows)
    const int qwA = sbk * 128 + w * 16;       // sub-tile A rows
    const int qwB = qwA + 64;                 // sub-tile B rows
    const int ntp = 2 * sbk + 2;              // tiles needed by B's diagonal
    const int split = sbk + 1;                // = ceil(ntp/2)
    const int t0 = hv ? split : 0;
    const int t1 = hv ? ntp : split;

    // Q fragments (B-operand of swapped QK^T): row = c, k = g*8.. (+32)
    bf16x8 qfA0 = *(const bf16x8*)&Qp[(size_t)(qwA + c) * DH + g * 8];
    bf16x8 qfA1 = *(const bf16x8*)&Qp[(size_t)(qwA + c) * DH + 32 + g * 8];
    bf16x8 qfB0 = *(const bf16x8*)&Qp[(size_t)(qwB + c) * DH + g * 8];
    bf16x8 qfB1 = *(const bf16x8*)&Qp[(size_t)(qwB + c) * DH + 32 + g * 8];

    f32x4 accA[4] = {}, accB[4] = {};
    float miA = NEG_INF, liA = 0.f;
    float miB = NEG_INF, liB = 0.f;

    STAGE(0, t0 * 64);
    __syncthreads();  // compiler drains vmcnt(0) before s_barrier
    int cur = 0;

    for (int t = t0; t < t1; ++t) {
      if (t + 1 < t1) STAGE(cur ^ 1, (t + 1) * 64);

      const char* Kb = (const char*)&Ks[cur][0];
      const char* Vb = (const char*)&Vs[cur][0];
      const bool aAct = (t < ntp - 1);   // block-uniform: A has keys this tile

      // K fragments: wave-invariant, read ONCE, used by both sub-tiles
      bf16x8 kf0[4], kf1[4];
#pragma unroll
      for (int ks = 0; ks < 4; ++ks) {
        const int rb = (ks * 16 + c) * 128;
        kf0[ks] = *(const bf16x8*)(Kb + rb + ((16 * g) ^ swb));
        kf1[ks] = *(const bf16x8*)(Kb + rb + ((64 + 16 * g) ^ swb));
      }
      // V fragments early -- independent of softmax, shared by both sub-tiles
      bf16x8 vf0[4], vf1[4];
#pragma unroll
      for (int dt = 0; dt < 4; ++dt) {
        const int rb = (dt * 16 + c) * 128;
        vf0[dt] = *(const bf16x8*)(Vb + rb + ((16 * g) ^ swb));
        vf1[dt] = *(const bf16x8*)(Vb + rb + ((64 + 16 * g) ^ swb));
      }

      // S tiles (SWAPPED): s[ks][i] = S[key = t*64+ks*16+g*4+i][q = qw + c]
      f32x4 sA[4], sB[4];
      if (aAct) {
#pragma unroll
        for (int ks = 0; ks < 4; ++ks) {
          f32x4 z = {0.f, 0.f, 0.f, 0.f};
          z = MFMA16(kf0[ks], qfA0, z);
          z = MFMA16(kf1[ks], qfA1, z);
          sA[ks] = z;
        }
      }
#pragma unroll
      for (int ks = 0; ks < 4; ++ks) {
        f32x4 z = {0.f, 0.f, 0.f, 0.f};
        z = MFMA16(kf0[ks], qfB0, z);
        z = MFMA16(kf1[ks], qfB1, z);
        sB[ks] = z;
      }

      // causal masks (diagonal tiles only)
      if (aAct && t == ntp - 2) {
        const int qq = qwA + c;
#pragma unroll
        for (int ks = 0; ks < 4; ++ks)
#pragma unroll
          for (int i = 0; i < 4; ++i)
            if (t * 64 + ks * 16 + g * 4 + i > qq) sA[ks][i] = NEG_INF;
      }
      if (t == ntp - 1) {
        const int qq = qwB + c;
#pragma unroll
        for (int ks = 0; ks < 4; ++ks)
#pragma unroll
          for (int i = 0; i < 4; ++i)
            if (t * 64 + ks * 16 + g * 4 + i > qq) sB[ks][i] = NEG_INF;
      }

      // ---- sub-tile A softmax + PV ----
      if (aAct) {
        float m0 = fmaxf(fmaxf(sA[0][0], sA[0][1]), fmaxf(sA[0][2], sA[0][3]));
        float m1 = fmaxf(fmaxf(sA[1][0], sA[1][1]), fmaxf(sA[1][2], sA[1][3]));
        float m2 = fmaxf(fmaxf(sA[2][0], sA[2][1]), fmaxf(sA[2][2], sA[2][3]));
        float m3 = fmaxf(fmaxf(sA[3][0], sA[3][1]), fmaxf(sA[3][2], sA[3][3]));
        float mloc = fmaxf(fmaxf(m0, m1), fmaxf(m2, m3));
        mloc = fmaxf(mloc, __shfl_xor(mloc, 16));
        mloc = fmaxf(mloc, __shfl_xor(mloc, 32));
        if (__ballot(mloc > miA + 8.0f) != 0ull) {
          const float mn = fmaxf(miA, mloc);
          const float scq = exp2f(miA - mn);
          miA = mn;
          liA *= scq;
          const float sv0 = __shfl(scq, 4 * g + 0);
          const float sv1 = __shfl(scq, 4 * g + 1);
          const float sv2 = __shfl(scq, 4 * g + 2);
          const float sv3 = __shfl(scq, 4 * g + 3);
#pragma unroll
          for (int dt = 0; dt < 4; ++dt) {
            accA[dt][0] *= sv0; accA[dt][1] *= sv1;
            accA[dt][2] *= sv2; accA[dt][3] *= sv3;
          }
        }
        float ls = 0.f;
#pragma unroll
        for (int ks = 0; ks < 4; ++ks) {
          float p0 = exp2f(sA[ks][0] - miA);
          float p1 = exp2f(sA[ks][1] - miA);
          float p2 = exp2f(sA[ks][2] - miA);
          float p3 = exp2f(sA[ks][3] - miA);
          ls += (p0 + p1) + (p2 + p3);
          uint2 pk;
          pk.x = pack_bf2(p0, p1);
          pk.y = pack_bf2(p2, p3);
          *(uint2*)(Pw + c * 128 + ((32 * ks + 8 * g) ^ swb)) = pk;
        }
        ls += __shfl_xor(ls, 16);
        ls += __shfl_xor(ls, 32);
        liA += ls;
        asm volatile("s_waitcnt lgkmcnt(0)" ::: "memory");
        bf16x8 pf0 = *(const bf16x8*)(Pw + c * 128 + ((16 * g) ^ swb));
        bf16x8 pf1 = *(const bf16x8*)(Pw + c * 128 + ((64 + 16 * g) ^ swb));
#pragma unroll
        for (int dt = 0; dt < 4; ++dt) {
          accA[dt] = MFMA16(pf0, vf0[dt], accA[dt]);
          accA[dt] = MFMA16(pf1, vf1[dt], accA[dt]);
        }
      }

      // ---- sub-tile B softmax + PV (reuses the same P buffer) ----
      {
        float m0 = fmaxf(fmaxf(sB[0][0], sB[0][1]), fmaxf(sB[0][2], sB[0][3]));
        float m1 = fmaxf(fmaxf(sB[1][0], sB[1][1]), fmaxf(sB[1][2], sB[1][3]));
        float m2 = fmaxf(fmaxf(sB[2][0], sB[2][1]), fmaxf(sB[2][2], sB[2][3]));
        float m3 = fmaxf(fmaxf(sB[3][0], sB[3][1]), fmaxf(sB[3][2], sB[3][3]));
        float mloc = fmaxf(fmaxf(m0, m1), fmaxf(m2, m3));
        mloc = fmaxf(mloc, __shfl_xor(mloc, 16));
        mloc = fmaxf(mloc, __shfl_xor(mloc, 32));
        if (__ballot(mloc > miB + 8.0f) != 0ull) {
          const float mn = fmaxf(miB, mloc);
          const float scq = exp2f(miB - mn);
          miB = mn;
          liB *= scq;
          const float sv0 = __shfl(scq, 4 * g + 0);
          const float sv1 = __shfl(scq, 4 * g + 1);
          const float sv2 = __shfl(scq, 4 * g + 2);
          const float sv3 = __shfl(scq, 4 * g + 3);
#pragma unroll
          for (int dt = 0; dt < 4; ++dt) {
            accB[dt][0] *= sv0; accB[dt][1] *= sv1;
            accB[dt][2] *= sv2; accB[dt][3] *= sv3;
          }
        }
        float ls = 0.f;
#pragma unroll
        for (int ks = 0; ks < 4; ++ks) {
          float p0 = exp2f(sB[ks][0] - miB);
          float p1 = exp2f(sB[ks][1] - miB);
          float p2 = exp2f(sB[ks][2] - miB);
          float p3 = exp2f(sB[ks][3] - miB);
          ls += (p0 + p1) + (p2 + p3);
          uint2 pk;
          pk.x = pack_bf2(p0, p1);
          pk.y = pack_bf2(p2, p3);
          *(uint2*)(Pw + c * 128 + ((32 * ks + 8 * g) ^ swb)) = pk;
        }
        ls += __shfl_xor(ls, 16);
        ls += __shfl_xor(ls, 32);
        liB += ls;
        asm volatile("s_waitcnt lgkmcnt(0)" ::: "memory");
        bf16x8 pf0 = *(const bf16x8*)(Pw + c * 128 + ((16 * g) ^ swb));
        bf16x8 pf1 = *(const bf16x8*)(Pw + c * 128 + ((64 + 16 * g) ^ swb));
#pragma unroll
        for (int dt = 0; dt < 4; ++dt) {
          accB[dt] = MFMA16(pf0, vf0[dt], accB[dt]);
          accB[dt] = MFMA16(pf1, vf1[dt], accB[dt]);
        }
      }

      // barrier: publishes prefetched tile (vmcnt drain) + buf-reuse guard
      __syncthreads();
      cur ^= 1;
    }

    // partial epilogues: o_norm (bf16) + s = mi + log2(li) per q-row
#pragma unroll
    for (int sub = 0; sub < 2; ++sub) {
      const int qw = sub ? qwB : qwA;
      const float mi = sub ? miB : miA;
      const float li = sub ? liB : liA;
      const f32x4* acc = sub ? accB : accA;
      if (g == 0) sbh[qw + c] = (li > 0.f) ? (mi + log2f(li)) : NEG_INF;
      const float liq0 = __shfl(li, 4 * g + 0);
      const float liq1 = __shfl(li, 4 * g + 1);
      const float liq2 = __shfl(li, 4 * g + 2);
      const float liq3 = __shfl(li, 4 * g + 3);
      const float inv[4] = {liq0 > 0.f ? 1.0f / liq0 : 0.f,
                            liq1 > 0.f ? 1.0f / liq1 : 0.f,
                            liq2 > 0.f ? 1.0f / liq2 : 0.f,
                            liq3 > 0.f ? 1.0f / liq3 : 0.f};
#pragma unroll
      for (int i = 0; i < 4; ++i) {
        const int qq = qw + g * 4 + i;
        const size_t base = ((size_t)bh * T_SEQ + qq) * DH;
#pragma unroll
        for (int dt = 0; dt < 4; ++dt)
          obh[base + dt * 16 + c] = f2bf(acc[dt][i] * inv[i]);
      }
    }
  }
#undef STAGE
}

// ---------------- split-K merge ----------------
// y[(b*T+q)*512 + h*64 + d] = (w0*o0 + w1*o1), w_i = 2^(s_i - max) normalized.
// 256 threads = 32 rows x 8 dim-segments (8 bf16 = 16B each).
__global__ __launch_bounds__(256) void merge_kernel(
    const unsigned short* __restrict__ ob0,
    const unsigned short* __restrict__ ob1,
    const float* __restrict__ sb,
    unsigned short* __restrict__ yb) {
  const int t = threadIdx.x;
  const int r = blockIdx.x * 32 + (t >> 3);   // global (bh,q) row, 0..65535
  const int dseg = (t & 7) * 8;
  const float s0 = sb[r];
  const float s1 = sb[NROWS + r];
  const float S = fmaxf(s0, s1);
  const float w0 = exp2f(s0 - S);
  const float w1 = exp2f(s1 - S);
  const float inv = 1.0f / (w0 + w1);
  const float a0 = w0 * inv, a1 = w1 * inv;
  const uint4 u0 = *(const uint4*)&ob0[(size_t)r * DH + dseg];
  const uint4 u1 = *(const uint4*)&ob1[(size_t)r * DH + dseg];
  const unsigned int* p0 = (const unsigned int*)&u0;
  const unsigned int* p1 = (const unsigned int*)&u1;
  unsigned int ow[4];
#pragma unroll
  for (int j = 0; j < 4; ++j) {
    const float lo0 = __uint_as_float(p0[j] << 16);
    const float hi0 = __uint_as_float(p0[j] & 0xffff0000u);
    const float lo1 = __uint_as_float(p1[j] << 16);
    const float hi1 = __uint_as_float(p1[j] & 0xffff0000u);
    ow[j] = pack_bf2(a0 * lo0 + a1 * lo1, a0 * hi0 + a1 * hi1);
  }
  const int bh = r >> 12, q = r & 4095;
  const int bb = bh >> 3, hh = bh & 7;
  *(uint4*)&yb[((size_t)(bb * T_SEQ + q)) * 512 + hh * DH + dseg] = *(uint4*)ow;
}

// ---------------- launch ----------------
extern "C" void kernel_launch(void* const* d_in, const int* in_sizes, int n_in,
                              void* d_out, int out_size, void* d_ws, size_t ws_size,
                              hipStream_t stream) {
  const float* x     = (const float*)d_in[0];
  const float* w_qkv = (const float*)d_in[1];
  const float* b_qkv = (const float*)d_in[2];
  const float* w_out = (const float*)d_in[3];
  const float* b_out = (const float*)d_in[4];
  float* out = (float*)d_out;

  char* p = (char*)d_ws;
  unsigned short* xb    = (unsigned short*)p; p += (size_t)8192 * 512 * 2;
  unsigned short* wqkvT = (unsigned short*)p; p += (size_t)1536 * 512 * 2;
  unsigned short* woutT = (unsigned short*)p; p += (size_t)512 * 512 * 2;
  unsigned short* qbuf  = (unsigned short*)p; p += (size_t)16 * T_SEQ * DH * 2;
  unsigned short* kbuf  = (unsigned short*)p; p += (size_t)16 * T_SEQ * DH * 2;
  unsigned short* vtbuf = (unsigned short*)p; p += (size_t)16 * T_SEQ * DH * 2;
  unsigned short* ybuf  = (unsigned short*)p; p += (size_t)8192 * 512 * 2;
  unsigned short* ob1   = (unsigned short*)p; p += (size_t)16 * T_SEQ * DH * 2;
  float*          sbuf  = (float*)p;          p += (size_t)2 * NROWS * 4;
  unsigned short* ob0   = xb;  // xb is dead after the QKV GEMM -- reuse

  cvt_x_kernel<<<4096, 256, 0, stream>>>(x, xb, 8192 * 512 / 4);
  cvt_T_kernel<<<3072, 256, 0, stream>>>(w_qkv, wqkvT, 1536, 1536 * 512);
  cvt_T_kernel<<<1024, 256, 0, stream>>>(w_out, woutT, 512, 512 * 512);

  // QKV projection: M=8192, N=1536, K=512
  gemm_bt<0><<<dim3(12, 64), 256, 0, stream>>>(xb, wqkvT, b_qkv, nullptr,
                                               qbuf, kbuf, vtbuf, 512);
  // attention: 128-q superblocks, paired + split-K (512 equal blocks)
  attn_kernel<<<dim3(16, 16, 2), 256, 0, stream>>>(qbuf, kbuf, vtbuf,
                                                   ob0, ob1, sbuf);
  merge_kernel<<<NROWS / 32, 256, 0, stream>>>(ob0, ob1, sbuf, ybuf);
  // output projection: M=8192, N=512, K=512
  gemm_bt<1><<<dim3(4, 64), 256, 0, stream>>>(ybuf, woutT, b_out, out,
                                              nullptr, nullptr, nullptr, 512);
}

// Round 12
// 143.806 us; speedup vs baseline: 1.1358x; 1.1358x over previous
//
#include <hip/hip_runtime.h>
#include <cstdint>
#include <cstddef>

// ---------------- types / helpers ----------------
typedef __attribute__((ext_vector_type(8)))  __bf16 bf16x8;
typedef __attribute__((ext_vector_type(4)))  float  f32x4;
typedef __attribute__((ext_vector_type(16))) float  f32x16;

#define MFMA16(a, b, c) __builtin_amdgcn_mfma_f32_16x16x32_bf16((a), (b), (c), 0, 0, 0)
#define MFMA32(a, b, c) __builtin_amdgcn_mfma_f32_32x32x16_bf16((a), (b), (c), 0, 0, 0)

#define T_SEQ 4096
#define NHEADS 8
#define DH 64
#define NROWS (2 * NHEADS * T_SEQ)   // 65536 total (bh, q) rows
#define NEG_INF (-__builtin_huge_valf())
// 1/sqrt(64) * log2(e)  (softmax done in exp2 domain)
#define SCALE_Q 0.18033688011112042f

__device__ __forceinline__ unsigned short f2bf(float f) {
  unsigned int u = __float_as_uint(f);
  u += 0x7fffu + ((u >> 16) & 1u);
  return (unsigned short)(u >> 16);
}

// pack two f32 -> two bf16 in one u32 (hardware cvt_pk, RNE; lo = low half)
__device__ __forceinline__ unsigned int cvtpk(float lo, float hi) {
  unsigned int r;
  asm("v_cvt_pk_bf16_f32 %0, %1, %2" : "=v"(r) : "v"(lo), "v"(hi));
  return r;
}

// v_permlane32_swap_b32 vdst, vsrc: vdst.hi(32:63) <-> vsrc.lo(0:31)
// (direction established empirically in R11: (b0,a0) order mis-assembled P,
//  (a0,b0) is HK's T12 order: low-key pair FIRST)
__device__ __forceinline__ void swap32(unsigned int& x, unsigned int& y) {
  asm("v_permlane32_swap_b32 %0, %1" : "+v"(x), "+v"(y));
}

// pack two f32 -> two bf16 in one u32 (round-half-up; a = low half)
__device__ __forceinline__ unsigned int pack_bf2(float a, float b) {
  unsigned int au = __float_as_uint(a) + 0x8000u;
  unsigned int bu = __float_as_uint(b) + 0x8000u;
  return (au >> 16) | (bu & 0xffff0000u);
}

// async global->LDS, 16B per lane. LDS dest = uniform base + lane*16.
__device__ __forceinline__ void gload16(const unsigned short* g, unsigned short* l) {
  __builtin_amdgcn_global_load_lds(
      (const __attribute__((address_space(1))) unsigned short*)g,
      (__attribute__((address_space(3))) unsigned short*)l, 16, 0, 0);
}

// ---------------- conversion kernels ----------------
__global__ void cvt_x_kernel(const float* __restrict__ x,
                             unsigned short* __restrict__ xb, int n4) {
  int i = blockIdx.x * blockDim.x + threadIdx.x;
  if (i >= n4) return;
  float4 v = ((const float4*)x)[i];
  ushort4 o;
  o.x = f2bf(v.x); o.y = f2bf(v.y); o.z = f2bf(v.z); o.w = f2bf(v.w);
  ((ushort4*)xb)[i] = o;
}

// w [512][N] (K=512 rows) -> wT [N][512] bf16
__global__ void cvt_T_kernel(const float* __restrict__ w,
                             unsigned short* __restrict__ wT, int N, int total) {
  int i = blockIdx.x * blockDim.x + threadIdx.x;
  if (i >= total) return;
  int n = i >> 9, k = i & 511;
  wT[i] = f2bf(w[(size_t)k * N + n]);
}

// ---------------- GEMM: C = A[M,K] * BT[N,K]^T + bias ----------------
// 128x128 block tile, BK=32, 4 waves (each a 64x64 quadrant), 16x16x32 MFMA.
// EPI==0: QKV epilogue (q/k -> [B*H][T][64], V -> transposed [B*H][64][T])
// EPI==1: fp32 output [M][512] with bias
template <int EPI>
__global__ __launch_bounds__(256) void gemm_bt(
    const unsigned short* __restrict__ A,
    const unsigned short* __restrict__ BT,
    const float* __restrict__ bias,
    float* __restrict__ outf,
    unsigned short* __restrict__ oq,
    unsigned short* __restrict__ ok,
    unsigned short* __restrict__ ovT,
    int K) {
  __shared__ alignas(16) unsigned short As[128 * 32];
  __shared__ alignas(16) unsigned short Bs[128 * 32];

  const int t = threadIdx.x;
  const int lane = t & 63;
  const int w = t >> 6;
  const int wr = (w >> 1) * 64;
  const int wc = (w & 1) * 64;
  const int g = lane >> 4, c = lane & 15;
  const int row0 = blockIdx.y * 128, col0 = blockIdx.x * 128;

  const int crow = t >> 2;          // 0..63
  const int ccol = (t & 3) * 8;     // 0,8,16,24
  const unsigned short* Ag0 = A + (size_t)(row0 + crow) * K + ccol;
  const unsigned short* Ag1 = A + (size_t)(row0 + 64 + crow) * K + ccol;
  const unsigned short* Bg0 = BT + (size_t)(col0 + crow) * K + ccol;
  const unsigned short* Bg1 = BT + (size_t)(col0 + 64 + crow) * K + ccol;

  f32x4 acc[4][4] = {};

  for (int k0 = 0; k0 < K; k0 += 32) {
    int4 a0 = *(const int4*)(Ag0 + k0);
    int4 a1 = *(const int4*)(Ag1 + k0);
    int4 b0 = *(const int4*)(Bg0 + k0);
    int4 b1 = *(const int4*)(Bg1 + k0);
    __syncthreads();
    *(int4*)&As[crow * 32 + ccol] = a0;
    *(int4*)&As[(64 + crow) * 32 + ccol] = a1;
    *(int4*)&Bs[crow * 32 + ccol] = b0;
    *(int4*)&Bs[(64 + crow) * 32 + ccol] = b1;
    __syncthreads();

    bf16x8 af[4], bfr[4];
#pragma unroll
    for (int m = 0; m < 4; ++m)
      af[m] = *(const bf16x8*)&As[(wr + m * 16 + c) * 32 + g * 8];
#pragma unroll
    for (int n = 0; n < 4; ++n)
      bfr[n] = *(const bf16x8*)&Bs[(wc + n * 16 + c) * 32 + g * 8];
#pragma unroll
    for (int m = 0; m < 4; ++m)
#pragma unroll
      for (int n = 0; n < 4; ++n)
        acc[m][n] = MFMA16(af[m], bfr[n], acc[m][n]);
  }

  // epilogue. D layout: row = g*4 + i, col = c (verified m89/m91 mapping)
#pragma unroll
  for (int m = 0; m < 4; ++m) {
#pragma unroll
    for (int n = 0; n < 4; ++n) {
      const int col = col0 + wc + n * 16 + c;
      const float bv = bias[col];
      if constexpr (EPI == 0) {
        const int which = col >> 9;          // wave-uniform (depends on block,n)
        const int h = (col >> 6) & 7;
        const int dh = col & 63;
        const int r0 = row0 + wr + m * 16 + g * 4;
        const int bb = r0 >> 12;             // r0 / T_SEQ (4 rows never cross)
        const int tt0 = r0 & 4095;
        if (which == 2) {
          // V transposed: vT[(bb*H + h)*64 + dh][tt0..tt0+3] -- contiguous
          ushort4 pk;
          pk.x = f2bf(acc[m][n][0] + bv);
          pk.y = f2bf(acc[m][n][1] + bv);
          pk.z = f2bf(acc[m][n][2] + bv);
          pk.w = f2bf(acc[m][n][3] + bv);
          *(ushort4*)&ovT[((size_t)((bb * NHEADS + h) * DH + dh)) * T_SEQ + tt0] = pk;
        } else {
          unsigned short* dst = (which == 0) ? oq : ok;
          const float sc = (which == 0) ? SCALE_Q : 1.0f;
#pragma unroll
          for (int i = 0; i < 4; ++i) {
            const size_t idx =
                ((size_t)((bb * NHEADS + h) * T_SEQ + tt0 + i)) * DH + dh;
            dst[idx] = f2bf((acc[m][n][i] + bv) * sc);
          }
        }
      } else {
#pragma unroll
        for (int i = 0; i < 4; ++i) {
          const int row = row0 + wr + m * 16 + g * 4 + i;
          outf[(size_t)row * 512 + col] = acc[m][n][i] + bv;
        }
      }
    }
  }
}

// ---------------- flash attention (causal, split-K, 32x32 MFMA) ----------
// grid (B*H, 16, 2). Block (bh, y, hv) runs two passes over 128-row
// q-superblocks (sb = y, 31-y), split-K half hv of each. Each wave owns ONE
// 32-row q-tile via 32x32x16 MFMA with BOTH products swapped:
//   S   = mfma32(K-frag, Q-frag)   -> lane holds q = lane&31, 32 keys in regs
//   acc = mfma32(vT-frag, P-frag)  -> acc keeps q lane-local (rescale = local)
// P never touches LDS: per 16-key step, exp2 -> v_cvt_pk_bf16_f32 x4 ->
// v_permlane32_swap_b32 x2 assembles the PV B-operand in registers (T12).
// Softmax reduces = 31 local ops + one shfl_xor(32). LDS = K,V dbuf only
// (32 KB). Defer-max, XOR-swizzle staging, pairing, split-K as before.
__global__ __launch_bounds__(256, 4) void attn_kernel(
    const unsigned short* __restrict__ qb,
    const unsigned short* __restrict__ kb,
    const unsigned short* __restrict__ vtb,
    unsigned short* __restrict__ ob0,
    unsigned short* __restrict__ ob1,
    float* __restrict__ sb) {
  const int bh = blockIdx.x;
  const int y = blockIdx.y;
  const int hv = blockIdx.z;
  const int w = threadIdx.x >> 6;
  const int lane = threadIdx.x & 63;
  const int q32 = lane & 31;          // lane-local q row (and d row for acc)
  const int h = lane >> 5;            // half index
  const int swb = (lane & 7) << 4;    // read-side xor (bytes), row&7 == lane&7

  // K tile: rows = key (64), cols = d (64, 128B). V tile: rows = d, cols = t.
  __shared__ alignas(16) unsigned short Ks[2][64 * 64];
  __shared__ alignas(16) unsigned short Vs[2][64 * 64];

  const unsigned short* Qp  = qb + (size_t)bh * T_SEQ * DH;
  const unsigned short* Kp  = kb + (size_t)bh * T_SEQ * DH;
  const unsigned short* VTp = vtb + (size_t)bh * DH * T_SEQ;

  unsigned short* obh = hv ? ob1 : ob0;
  float* sbh = sb + (size_t)hv * NROWS + (size_t)bh * T_SEQ;

  // staging: wave w stages LDS rows 16w..16w+15 of both tiles (2 gloads each).
  // source column pre-swizzled: row r keeps byte-col cb at cb ^ ((r&7)<<4);
  // gload instr writes rows q*8+l8 linearly, so swizzle = 8*(lc ^ l8) elems.
  const int l8 = lane >> 3, lc = lane & 7;
  const int swzE = 8 * (lc ^ l8);
  const unsigned short* Ksrc0 = Kp + (size_t)(16 * w + l8) * DH + swzE;
  const unsigned short* Ksrc1 = Kp + (size_t)(16 * w + 8 + l8) * DH + swzE;
  const unsigned short* Vsrc0 = VTp + (size_t)(16 * w + l8) * T_SEQ + swzE;
  const unsigned short* Vsrc1 = VTp + (size_t)(16 * w + 8 + l8) * T_SEQ + swzE;

#define STAGE(B, J0) do {                                              \
    gload16(Ksrc0 + (size_t)(J0) * DH, &Ks[B][(2 * w) * 512]);         \
    gload16(Ksrc1 + (size_t)(J0) * DH, &Ks[B][(2 * w + 1) * 512]);     \
    gload16(Vsrc0 + (J0), &Vs[B][(2 * w) * 512]);                      \
    gload16(Vsrc1 + (J0), &Vs[B][(2 * w + 1) * 512]);                  \
  } while (0)

  for (int pass = 0; pass < 2; ++pass) {
    const int sbk = pass ? (31 - y) : y;      // q-superblock (128 rows)
    const int qw = sbk * 128 + w * 32;        // this wave's 32 q-rows
    const int ntp = 2 * sbk + 2;              // tiles needed by wave 3
    const int split = sbk + 1;
    const int t0 = hv ? split : 0;
    const int t1 = hv ? ntp : split;
    const int tlast = (qw + 31) >> 6;         // this wave's diagonal tile

    // Q fragments (B-operand of swapped QK): col=q=lane&31, k=16d+8h+e
    bf16x8 qf[4];
#pragma unroll
    for (int d = 0; d < 4; ++d)
      qf[d] = *(const bf16x8*)&Qp[(size_t)(qw + q32) * DH + 16 * d + 8 * h];

    f32x16 acc0 = {}, acc1 = {};
    float mi = NEG_INF;   // running row-max for q = qw + q32 (exp2 domain)
    float li = 0.f;       // running row-sum

    STAGE(0, t0 * 64);
    __syncthreads();  // compiler drains vmcnt(0) before s_barrier
    int cur = 0;

    for (int t = t0; t < t1; ++t) {
      if (t + 1 < t1) STAGE(cur ^ 1, (t + 1) * 64);

      if (t <= tlast) {  // wave-uniform; no barriers inside
        const char* Kb = (const char*)&Ks[cur][0];
        const char* Vb = (const char*)&Vs[cur][0];

        // S = K.Q^T (swapped): s{0,1}[r] = S[key=ks*32+(r&3)+8(r>>2)+4h][q]
        f32x16 s0 = {}, s1 = {};
#pragma unroll
        for (int d = 0; d < 4; ++d) {
          bf16x8 kf0 = *(const bf16x8*)(Kb + q32 * 128 +
                                        ((32 * d + 16 * h) ^ swb));
          bf16x8 kf1 = *(const bf16x8*)(Kb + (32 + q32) * 128 +
                                        ((32 * d + 16 * h) ^ swb));
          s0 = MFMA32(kf0, qf[d], s0);
          s1 = MFMA32(kf1, qf[d], s1);
        }

        if (t == tlast) {  // diagonal tile: causal mask (key > q)
          const int qq = qw + q32;
          const int kb0 = t * 64 + 4 * h;
#pragma unroll
          for (int r = 0; r < 16; ++r) {
            const int ko = kb0 + (r & 3) + 8 * (r >> 2);
            if (ko > qq) s0[r] = NEG_INF;
            if (ko + 32 > qq) s1[r] = NEG_INF;
          }
        }

        // row max: 31-op local tree + one cross-half shuffle
        float mv[8];
#pragma unroll
        for (int i = 0; i < 8; ++i)
          mv[i] = fmaxf(fmaxf(s0[2 * i], s0[2 * i + 1]),
                        fmaxf(s1[2 * i], s1[2 * i + 1]));
        float mloc = fmaxf(fmaxf(fmaxf(mv[0], mv[1]), fmaxf(mv[2], mv[3])),
                           fmaxf(fmaxf(mv[4], mv[5]), fmaxf(mv[6], mv[7])));
        mloc = fmaxf(mloc, __shfl_xor(mloc, 32));

        // defer-max: only rescale when some row grew past THR=8
        if (__ballot(mloc > mi + 8.0f) != 0ull) {
          const float mn = fmaxf(mi, mloc);
          const float scq = exp2f(mi - mn);
          mi = mn;
          li *= scq;
#pragma unroll
          for (int r = 0; r < 16; ++r) { acc0[r] *= scq; acc1[r] *= scq; }
        }

        // per 16-key step: exp2 -> cvt_pk -> permlane swap -> PV MFMA
        float ls = 0.f;
#pragma unroll
        for (int kk = 0; kk < 4; ++kk) {
          float pv[8];
#pragma unroll
          for (int e = 0; e < 8; ++e) {
            const float sv = (kk < 2) ? s0[(kk & 1) * 8 + e]
                                      : s1[(kk & 1) * 8 + e];
            pv[e] = exp2f(sv - mi);
          }
          ls += ((pv[0] + pv[1]) + (pv[2] + pv[3])) +
                ((pv[4] + pv[5]) + (pv[6] + pv[7]));
          // own pairs: a0=keys 4h+{0,1}, a1=4h+{2,3}, b0=8+4h+{0,1}, b1=...
          unsigned int a0 = cvtpk(pv[0], pv[1]);
          unsigned int a1 = cvtpk(pv[2], pv[3]);
          unsigned int b0 = cvtpk(pv[4], pv[5]);
          unsigned int b1 = cvtpk(pv[6], pv[7]);
          // swap32(a,b): a.hi <-> b.lo (low-key pair FIRST, per HK T12).
          // after: h=0 lane: a0=own{0,1}, b0=partner{4,5};
          //        h=1 lane: a0=partner{8,9}, b0=own{12,13}
          // => u[0..3] = keys 8h+{0,1},{2,3},{4,5},{6,7}  (exactly B-operand)
          swap32(a0, b0);
          swap32(a1, b1);
          union { unsigned int u[4]; bf16x8 v; } pf;
          pf.u[0] = a0; pf.u[1] = a1; pf.u[2] = b0; pf.u[3] = b1;

          bf16x8 vf0 = *(const bf16x8*)(Vb + q32 * 128 +
                                        ((32 * kk + 16 * h) ^ swb));
          bf16x8 vf1 = *(const bf16x8*)(Vb + (32 + q32) * 128 +
                                        ((32 * kk + 16 * h) ^ swb));
          acc0 = MFMA32(vf0, pf.v, acc0);
          acc1 = MFMA32(vf1, pf.v, acc1);
        }
        ls += __shfl_xor(ls, 32);
        li += ls;
      }

      // barrier: publishes prefetched tile (vmcnt drain) + buf-reuse guard
      __syncthreads();
      cur ^= 1;
    }

    // partial epilogue: o_norm (bf16) + s = mi + log2(li) per q-row.
    // acc: lane q = lane&31, d = (r&3)+8(r>>2)+4h (+32 for acc1)
    if (lane < 32) sbh[qw + lane] = (li > 0.f) ? (mi + log2f(li)) : NEG_INF;
    const float inv = (li > 0.f) ? 1.0f / li : 0.f;
    const size_t base = ((size_t)bh * T_SEQ + qw + q32) * DH;
#pragma unroll
    for (int dt = 0; dt < 2; ++dt) {
#pragma unroll
      for (int p4 = 0; p4 < 4; ++p4) {
        const float v0 = (dt ? acc1[4 * p4 + 0] : acc0[4 * p4 + 0]) * inv;
        const float v1 = (dt ? acc1[4 * p4 + 1] : acc0[4 * p4 + 1]) * inv;
        const float v2 = (dt ? acc1[4 * p4 + 2] : acc0[4 * p4 + 2]) * inv;
        const float v3 = (dt ? acc1[4 * p4 + 3] : acc0[4 * p4 + 3]) * inv;
        const int d0 = 32 * dt + 8 * p4 + 4 * h;
        *(unsigned int*)&obh[base + d0]     = cvtpk(v0, v1);
        *(unsigned int*)&obh[base + d0 + 2] = cvtpk(v2, v3);
      }
    }
  }
#undef STAGE
}

// ---------------- split-K merge ----------------
// y[(b*T+q)*512 + h*64 + d] = (w0*o0 + w1*o1), w_i = 2^(s_i - max) normalized.
// 256 threads = 32 rows x 8 dim-segments (8 bf16 = 16B each).
__global__ __launch_bounds__(256) void merge_kernel(
    const unsigned short* __restrict__ ob0,
    const unsigned short* __restrict__ ob1,
    const float* __restrict__ sb,
    unsigned short* __restrict__ yb) {
  const int t = threadIdx.x;
  const int r = blockIdx.x * 32 + (t >> 3);   // global (bh,q) row, 0..65535
  const int dseg = (t & 7) * 8;
  const float s0 = sb[r];
  const float s1 = sb[NROWS + r];
  const float S = fmaxf(s0, s1);
  const float w0 = exp2f(s0 - S);
  const float w1 = exp2f(s1 - S);
  const float inv = 1.0f / (w0 + w1);
  const float a0 = w0 * inv, a1 = w1 * inv;
  const uint4 u0 = *(const uint4*)&ob0[(size_t)r * DH + dseg];
  const uint4 u1 = *(const uint4*)&ob1[(size_t)r * DH + dseg];
  const unsigned int* p0 = (const unsigned int*)&u0;
  const unsigned int* p1 = (const unsigned int*)&u1;
  unsigned int ow[4];
#pragma unroll
  for (int j = 0; j < 4; ++j) {
    const float lo0 = __uint_as_float(p0[j] << 16);
    const float hi0 = __uint_as_float(p0[j] & 0xffff0000u);
    const float lo1 = __uint_as_float(p1[j] << 16);
    const float hi1 = __uint_as_float(p1[j] & 0xffff0000u);
    ow[j] = pack_bf2(a0 * lo0 + a1 * lo1, a0 * hi0 + a1 * hi1);
  }
  const int bh = r >> 12, q = r & 4095;
  const int bb = bh >> 3, hh = bh & 7;
  *(uint4*)&yb[((size_t)(bb * T_SEQ + q)) * 512 + hh * DH + dseg] = *(uint4*)ow;
}

// ---------------- launch ----------------
extern "C" void kernel_launch(void* const* d_in, const int* in_sizes, int n_in,
                              void* d_out, int out_size, void* d_ws, size_t ws_size,
                              hipStream_t stream) {
  const float* x     = (const float*)d_in[0];
  const float* w_qkv = (const float*)d_in[1];
  const float* b_qkv = (const float*)d_in[2];
  const float* w_out = (const float*)d_in[3];
  const float* b_out = (const float*)d_in[4];
  float* out = (float*)d_out;

  char* p = (char*)d_ws;
  unsigned short* xb    = (unsigned short*)p; p += (size_t)8192 * 512 * 2;
  unsigned short* wqkvT = (unsigned short*)p; p += (size_t)1536 * 512 * 2;
  unsigned short* woutT = (unsigned short*)p; p += (size_t)512 * 512 * 2;
  unsigned short* qbuf  = (unsigned short*)p; p += (size_t)16 * T_SEQ * DH * 2;
  unsigned short* kbuf  = (unsigned short*)p; p += (size_t)16 * T_SEQ * DH * 2;
  unsigned short* vtbuf = (unsigned short*)p; p += (size_t)16 * T_SEQ * DH * 2;
  unsigned short* ybuf  = (unsigned short*)p; p += (size_t)8192 * 512 * 2;
  unsigned short* ob1   = (unsigned short*)p; p += (size_t)16 * T_SEQ * DH * 2;
  float*          sbuf  = (float*)p;          p += (size_t)2 * NROWS * 4;
  unsigned short* ob0   = xb;  // xb is dead after the QKV GEMM -- reuse

  cvt_x_kernel<<<4096, 256, 0, stream>>>(x, xb, 8192 * 512 / 4);
  cvt_T_kernel<<<3072, 256, 0, stream>>>(w_qkv, wqkvT, 1536, 1536 * 512);
  cvt_T_kernel<<<1024, 256, 0, stream>>>(w_out, woutT, 512, 512 * 512);

  // QKV projection: M=8192, N=1536, K=512
  gemm_bt<0><<<dim3(12, 64), 256, 0, stream>>>(xb, wqkvT, b_qkv, nullptr,
                                               qbuf, kbuf, vtbuf, 512);
  // attention: 128-q superblocks, paired + split-K (512 equal blocks)
  attn_kernel<<<dim3(16, 16, 2), 256, 0, stream>>>(qbuf, kbuf, vtbuf,
                                                   ob0, ob1, sbuf);
  merge_kernel<<<NROWS / 32, 256, 0, stream>>>(ob0, ob1, sbuf, ybuf);
  // output projection: M=8192, N=512, K=512
  gemm_bt<1><<<dim3(4, 64), 256, 0, stream>>>(ybuf, woutT, b_out, out,
                                              nullptr, nullptr, nullptr, 512);
}

// Round 13
// 138.082 us; speedup vs baseline: 1.1829x; 1.0415x over previous
//
#include <hip/hip_runtime.h>
#include <cstdint>
#include <cstddef>

// ---------------- types / helpers ----------------
typedef __attribute__((ext_vector_type(8)))  __bf16 bf16x8;
typedef __attribute__((ext_vector_type(4)))  float  f32x4;
typedef __attribute__((ext_vector_type(16))) float  f32x16;

#define MFMA16(a, b, c) __builtin_amdgcn_mfma_f32_16x16x32_bf16((a), (b), (c), 0, 0, 0)
#define MFMA32(a, b, c) __builtin_amdgcn_mfma_f32_32x32x16_bf16((a), (b), (c), 0, 0, 0)

#define T_SEQ 4096
#define NHEADS 8
#define DH 64
#define NROWS (2 * NHEADS * T_SEQ)   // 65536 total (bh, q) rows
#define NSPLIT 4
#define NEG_INF (-__builtin_huge_valf())
// 1/sqrt(64) * log2(e)  (softmax done in exp2 domain)
#define SCALE_Q 0.18033688011112042f

__device__ __forceinline__ unsigned short f2bf(float f) {
  unsigned int u = __float_as_uint(f);
  u += 0x7fffu + ((u >> 16) & 1u);
  return (unsigned short)(u >> 16);
}

// pack two f32 -> two bf16 in one u32 (hardware cvt_pk, RNE; lo = low half)
__device__ __forceinline__ unsigned int cvtpk(float lo, float hi) {
  unsigned int r;
  asm("v_cvt_pk_bf16_f32 %0, %1, %2" : "=v"(r) : "v"(lo), "v"(hi));
  return r;
}

// v_permlane32_swap_b32 vdst, vsrc: vdst.hi(32:63) <-> vsrc.lo(0:31)
// ((a,b) low-key-pair-first order verified on HW in R12)
__device__ __forceinline__ void swap32(unsigned int& x, unsigned int& y) {
  asm("v_permlane32_swap_b32 %0, %1" : "+v"(x), "+v"(y));
}

// pack two f32 -> two bf16 in one u32 (round-half-up; a = low half)
__device__ __forceinline__ unsigned int pack_bf2(float a, float b) {
  unsigned int au = __float_as_uint(a) + 0x8000u;
  unsigned int bu = __float_as_uint(b) + 0x8000u;
  return (au >> 16) | (bu & 0xffff0000u);
}

// async global->LDS, 16B per lane. LDS dest = uniform base + lane*16.
__device__ __forceinline__ void gload16(const unsigned short* g, unsigned short* l) {
  __builtin_amdgcn_global_load_lds(
      (const __attribute__((address_space(1))) unsigned short*)g,
      (__attribute__((address_space(3))) unsigned short*)l, 16, 0, 0);
}

// ---------------- conversion kernels ----------------
__global__ void cvt_x_kernel(const float* __restrict__ x,
                             unsigned short* __restrict__ xb, int n4) {
  int i = blockIdx.x * blockDim.x + threadIdx.x;
  if (i >= n4) return;
  float4 v = ((const float4*)x)[i];
  ushort4 o;
  o.x = f2bf(v.x); o.y = f2bf(v.y); o.z = f2bf(v.z); o.w = f2bf(v.w);
  ((ushort4*)xb)[i] = o;
}

// w [512][N] (K=512 rows) -> wT [N][512] bf16
__global__ void cvt_T_kernel(const float* __restrict__ w,
                             unsigned short* __restrict__ wT, int N, int total) {
  int i = blockIdx.x * blockDim.x + threadIdx.x;
  if (i >= total) return;
  int n = i >> 9, k = i & 511;
  wT[i] = f2bf(w[(size_t)k * N + n]);
}

// ---------------- GEMM: C = A[M,K] * BT[N,K]^T + bias ----------------
// 128x128 block tile, BK=32, 4 waves (each a 64x64 quadrant), 16x16x32 MFMA.
// EPI==0: QKV epilogue (q/k -> [B*H][T][64], V -> transposed [B*H][64][T])
// EPI==1: fp32 output [M][512] with bias
template <int EPI>
__global__ __launch_bounds__(256) void gemm_bt(
    const unsigned short* __restrict__ A,
    const unsigned short* __restrict__ BT,
    const float* __restrict__ bias,
    float* __restrict__ outf,
    unsigned short* __restrict__ oq,
    unsigned short* __restrict__ ok,
    unsigned short* __restrict__ ovT,
    int K) {
  __shared__ alignas(16) unsigned short As[128 * 32];
  __shared__ alignas(16) unsigned short Bs[128 * 32];

  const int t = threadIdx.x;
  const int lane = t & 63;
  const int w = t >> 6;
  const int wr = (w >> 1) * 64;
  const int wc = (w & 1) * 64;
  const int g = lane >> 4, c = lane & 15;
  const int row0 = blockIdx.y * 128, col0 = blockIdx.x * 128;

  const int crow = t >> 2;          // 0..63
  const int ccol = (t & 3) * 8;     // 0,8,16,24
  const unsigned short* Ag0 = A + (size_t)(row0 + crow) * K + ccol;
  const unsigned short* Ag1 = A + (size_t)(row0 + 64 + crow) * K + ccol;
  const unsigned short* Bg0 = BT + (size_t)(col0 + crow) * K + ccol;
  const unsigned short* Bg1 = BT + (size_t)(col0 + 64 + crow) * K + ccol;

  f32x4 acc[4][4] = {};

  for (int k0 = 0; k0 < K; k0 += 32) {
    int4 a0 = *(const int4*)(Ag0 + k0);
    int4 a1 = *(const int4*)(Ag1 + k0);
    int4 b0 = *(const int4*)(Bg0 + k0);
    int4 b1 = *(const int4*)(Bg1 + k0);
    __syncthreads();
    *(int4*)&As[crow * 32 + ccol] = a0;
    *(int4*)&As[(64 + crow) * 32 + ccol] = a1;
    *(int4*)&Bs[crow * 32 + ccol] = b0;
    *(int4*)&Bs[(64 + crow) * 32 + ccol] = b1;
    __syncthreads();

    bf16x8 af[4], bfr[4];
#pragma unroll
    for (int m = 0; m < 4; ++m)
      af[m] = *(const bf16x8*)&As[(wr + m * 16 + c) * 32 + g * 8];
#pragma unroll
    for (int n = 0; n < 4; ++n)
      bfr[n] = *(const bf16x8*)&Bs[(wc + n * 16 + c) * 32 + g * 8];
#pragma unroll
    for (int m = 0; m < 4; ++m)
#pragma unroll
      for (int n = 0; n < 4; ++n)
        acc[m][n] = MFMA16(af[m], bfr[n], acc[m][n]);
  }

  // epilogue. D layout: row = g*4 + i, col = c (verified m89/m91 mapping)
#pragma unroll
  for (int m = 0; m < 4; ++m) {
#pragma unroll
    for (int n = 0; n < 4; ++n) {
      const int col = col0 + wc + n * 16 + c;
      const float bv = bias[col];
      if constexpr (EPI == 0) {
        const int which = col >> 9;          // wave-uniform (depends on block,n)
        const int h = (col >> 6) & 7;
        const int dh = col & 63;
        const int r0 = row0 + wr + m * 16 + g * 4;
        const int bb = r0 >> 12;             // r0 / T_SEQ (4 rows never cross)
        const int tt0 = r0 & 4095;
        if (which == 2) {
          // V transposed: vT[(bb*H + h)*64 + dh][tt0..tt0+3] -- contiguous
          ushort4 pk;
          pk.x = f2bf(acc[m][n][0] + bv);
          pk.y = f2bf(acc[m][n][1] + bv);
          pk.z = f2bf(acc[m][n][2] + bv);
          pk.w = f2bf(acc[m][n][3] + bv);
          *(ushort4*)&ovT[((size_t)((bb * NHEADS + h) * DH + dh)) * T_SEQ + tt0] = pk;
        } else {
          unsigned short* dst = (which == 0) ? oq : ok;
          const float sc = (which == 0) ? SCALE_Q : 1.0f;
#pragma unroll
          for (int i = 0; i < 4; ++i) {
            const size_t idx =
                ((size_t)((bb * NHEADS + h) * T_SEQ + tt0 + i)) * DH + dh;
            dst[idx] = f2bf((acc[m][n][i] + bv) * sc);
          }
        }
      } else {
#pragma unroll
        for (int i = 0; i < 4; ++i) {
          const int row = row0 + wr + m * 16 + g * 4 + i;
          outf[(size_t)row * 512 + col] = acc[m][n][i] + bv;
        }
      }
    }
  }
}

// ---------------- flash attention (causal, 4-way split-K, 32x32 MFMA) -----
// grid (B*H, 16, 4). Block (bh, y, hv) runs two passes over 128-row
// q-superblocks (sb = y, 31-y), key-tile QUARTER hv of each:
// [ (ntp*hv)>>2, (ntp*(hv+1))>>2 ). Pairing keeps every block at ~16-17
// tiles; 1024 equal blocks = 4 blocks/CU (128 KB LDS, 64 VGPR) = 4 waves/
// SIMD -- double R12's overlap depth for the serial QK->softmax->PV chain.
// Empty quarters are benign (li=0 -> s=-inf -> merge weight 0; tile 0 of
// each row lies in exactly one quarter so weights never all vanish).
// Per wave: 32 q-rows via 32x32x16 MFMA, both products swapped; P stays in
// registers via cvt_pk + permlane32_swap (T12). LDS = K,V dbuf only.
__global__ __launch_bounds__(256, 4) void attn_kernel(
    const unsigned short* __restrict__ qb,
    const unsigned short* __restrict__ kb,
    const unsigned short* __restrict__ vtb,
    unsigned short* __restrict__ opart,   // NSPLIT partials, contiguous
    float* __restrict__ sb) {
  const int bh = blockIdx.x;
  const int y = blockIdx.y;
  const int hv = blockIdx.z;
  const int w = threadIdx.x >> 6;
  const int lane = threadIdx.x & 63;
  const int q32 = lane & 31;          // lane-local q row (and d row for acc)
  const int h = lane >> 5;            // half index
  const int swb = (lane & 7) << 4;    // read-side xor (bytes), row&7 == lane&7

  // K tile: rows = key (64), cols = d (64, 128B). V tile: rows = d, cols = t.
  __shared__ alignas(16) unsigned short Ks[2][64 * 64];
  __shared__ alignas(16) unsigned short Vs[2][64 * 64];

  const unsigned short* Qp  = qb + (size_t)bh * T_SEQ * DH;
  const unsigned short* Kp  = kb + (size_t)bh * T_SEQ * DH;
  const unsigned short* VTp = vtb + (size_t)bh * DH * T_SEQ;

  unsigned short* obh = opart + (size_t)hv * NROWS * DH;
  float* sbh = sb + (size_t)hv * NROWS + (size_t)bh * T_SEQ;

  // staging: wave w stages LDS rows 16w..16w+15 of both tiles (2 gloads each).
  // source column pre-swizzled: row r keeps byte-col cb at cb ^ ((r&7)<<4);
  // gload instr writes rows q*8+l8 linearly, so swizzle = 8*(lc ^ l8) elems.
  const int l8 = lane >> 3, lc = lane & 7;
  const int swzE = 8 * (lc ^ l8);
  const unsigned short* Ksrc0 = Kp + (size_t)(16 * w + l8) * DH + swzE;
  const unsigned short* Ksrc1 = Kp + (size_t)(16 * w + 8 + l8) * DH + swzE;
  const unsigned short* Vsrc0 = VTp + (size_t)(16 * w + l8) * T_SEQ + swzE;
  const unsigned short* Vsrc1 = VTp + (size_t)(16 * w + 8 + l8) * T_SEQ + swzE;

#define STAGE(B, J0) do {                                              \
    gload16(Ksrc0 + (size_t)(J0) * DH, &Ks[B][(2 * w) * 512]);         \
    gload16(Ksrc1 + (size_t)(J0) * DH, &Ks[B][(2 * w + 1) * 512]);     \
    gload16(Vsrc0 + (J0), &Vs[B][(2 * w) * 512]);                      \
    gload16(Vsrc1 + (J0), &Vs[B][(2 * w + 1) * 512]);                  \
  } while (0)

  for (int pass = 0; pass < 2; ++pass) {
    const int sbk = pass ? (31 - y) : y;      // q-superblock (128 rows)
    const int qw = sbk * 128 + w * 32;        // this wave's 32 q-rows
    const int ntp = 2 * sbk + 2;              // tiles needed by wave 3
    const int t0 = (ntp * hv) >> 2;           // quarter range [t0, t1)
    const int t1 = (ntp * (hv + 1)) >> 2;
    const int tlast = (qw + 31) >> 6;         // this wave's diagonal tile

    // Q fragments (B-operand of swapped QK): col=q=lane&31, k=16d+8h+e
    bf16x8 qf[4];
#pragma unroll
    for (int d = 0; d < 4; ++d)
      qf[d] = *(const bf16x8*)&Qp[(size_t)(qw + q32) * DH + 16 * d + 8 * h];

    f32x16 acc0 = {}, acc1 = {};
    float mi = NEG_INF;   // running row-max for q = qw + q32 (exp2 domain)
    float li = 0.f;       // running row-sum

    STAGE(0, t0 * 64);
    __syncthreads();  // compiler drains vmcnt(0) before s_barrier
    int cur = 0;

    for (int t = t0; t < t1; ++t) {
      if (t + 1 < t1) STAGE(cur ^ 1, (t + 1) * 64);

      if (t <= tlast) {  // wave-uniform; no barriers inside
        const char* Kb = (const char*)&Ks[cur][0];
        const char* Vb = (const char*)&Vs[cur][0];

        // S = K.Q^T (swapped): s{0,1}[r] = S[key=ks*32+(r&3)+8(r>>2)+4h][q]
        f32x16 s0 = {}, s1 = {};
#pragma unroll
        for (int d = 0; d < 4; ++d) {
          bf16x8 kf0 = *(const bf16x8*)(Kb + q32 * 128 +
                                        ((32 * d + 16 * h) ^ swb));
          bf16x8 kf1 = *(const bf16x8*)(Kb + (32 + q32) * 128 +
                                        ((32 * d + 16 * h) ^ swb));
          s0 = MFMA32(kf0, qf[d], s0);
          s1 = MFMA32(kf1, qf[d], s1);
        }

        if (t == tlast) {  // diagonal tile: causal mask (key > q)
          const int qq = qw + q32;
          const int kb0 = t * 64 + 4 * h;
#pragma unroll
          for (int r = 0; r < 16; ++r) {
            const int ko = kb0 + (r & 3) + 8 * (r >> 2);
            if (ko > qq) s0[r] = NEG_INF;
            if (ko + 32 > qq) s1[r] = NEG_INF;
          }
        }

        // row max: 31-op local tree + one cross-half shuffle
        float mv[8];
#pragma unroll
        for (int i = 0; i < 8; ++i)
          mv[i] = fmaxf(fmaxf(s0[2 * i], s0[2 * i + 1]),
                        fmaxf(s1[2 * i], s1[2 * i + 1]));
        float mloc = fmaxf(fmaxf(fmaxf(mv[0], mv[1]), fmaxf(mv[2], mv[3])),
                           fmaxf(fmaxf(mv[4], mv[5]), fmaxf(mv[6], mv[7])));
        mloc = fmaxf(mloc, __shfl_xor(mloc, 32));

        // defer-max: only rescale when some row grew past THR=8
        if (__ballot(mloc > mi + 8.0f) != 0ull) {
          const float mn = fmaxf(mi, mloc);
          const float scq = exp2f(mi - mn);
          mi = mn;
          li *= scq;
#pragma unroll
          for (int r = 0; r < 16; ++r) { acc0[r] *= scq; acc1[r] *= scq; }
        }

        // per 16-key step: exp2 -> cvt_pk -> permlane swap -> PV MFMA
        float ls = 0.f;
#pragma unroll
        for (int kk = 0; kk < 4; ++kk) {
          float pv[8];
#pragma unroll
          for (int e = 0; e < 8; ++e) {
            const float sv = (kk < 2) ? s0[(kk & 1) * 8 + e]
                                      : s1[(kk & 1) * 8 + e];
            pv[e] = exp2f(sv - mi);
          }
          ls += ((pv[0] + pv[1]) + (pv[2] + pv[3])) +
                ((pv[4] + pv[5]) + (pv[6] + pv[7]));
          // own pairs: a0=keys 4h+{0,1}, a1=4h+{2,3}, b0=8+4h+{0,1}, b1=...
          unsigned int a0 = cvtpk(pv[0], pv[1]);
          unsigned int a1 = cvtpk(pv[2], pv[3]);
          unsigned int b0 = cvtpk(pv[4], pv[5]);
          unsigned int b1 = cvtpk(pv[6], pv[7]);
          // swap32(a,b): a.hi <-> b.lo (low-key pair FIRST, HW-verified R12)
          swap32(a0, b0);
          swap32(a1, b1);
          union { unsigned int u[4]; bf16x8 v; } pf;
          pf.u[0] = a0; pf.u[1] = a1; pf.u[2] = b0; pf.u[3] = b1;

          bf16x8 vf0 = *(const bf16x8*)(Vb + q32 * 128 +
                                        ((32 * kk + 16 * h) ^ swb));
          bf16x8 vf1 = *(const bf16x8*)(Vb + (32 + q32) * 128 +
                                        ((32 * kk + 16 * h) ^ swb));
          acc0 = MFMA32(vf0, pf.v, acc0);
          acc1 = MFMA32(vf1, pf.v, acc1);
        }
        ls += __shfl_xor(ls, 32);
        li += ls;
      }

      // barrier: publishes prefetched tile (vmcnt drain) + buf-reuse guard
      __syncthreads();
      cur ^= 1;
    }

    // partial epilogue: o_norm (bf16) + s = mi + log2(li) per q-row.
    // acc: lane q = lane&31, d = (r&3)+8(r>>2)+4h (+32 for acc1)
    if (lane < 32) sbh[qw + lane] = (li > 0.f) ? (mi + log2f(li)) : NEG_INF;
    const float inv = (li > 0.f) ? 1.0f / li : 0.f;
    const size_t base = ((size_t)bh * T_SEQ + qw + q32) * DH;
#pragma unroll
    for (int dt = 0; dt < 2; ++dt) {
#pragma unroll
      for (int p4 = 0; p4 < 4; ++p4) {
        const float v0 = (dt ? acc1[4 * p4 + 0] : acc0[4 * p4 + 0]) * inv;
        const float v1 = (dt ? acc1[4 * p4 + 1] : acc0[4 * p4 + 1]) * inv;
        const float v2 = (dt ? acc1[4 * p4 + 2] : acc0[4 * p4 + 2]) * inv;
        const float v3 = (dt ? acc1[4 * p4 + 3] : acc0[4 * p4 + 3]) * inv;
        const int d0 = 32 * dt + 8 * p4 + 4 * h;
        *(unsigned int*)&obh[base + d0]     = cvtpk(v0, v1);
        *(unsigned int*)&obh[base + d0 + 2] = cvtpk(v2, v3);
      }
    }
  }
#undef STAGE
}

// ---------------- split-K merge (4 partials) ----------------
// y[(b*T+q)*512 + h*64 + d] = sum_i w_i * o_i, w_i = 2^(s_i - max) normalized.
// 256 threads = 32 rows x 8 dim-segments (8 bf16 = 16B each).
__global__ __launch_bounds__(256) void merge_kernel(
    const unsigned short* __restrict__ opart,
    const float* __restrict__ sb,
    unsigned short* __restrict__ yb) {
  const int t = threadIdx.x;
  const int r = blockIdx.x * 32 + (t >> 3);   // global (bh,q) row, 0..65535
  const int dseg = (t & 7) * 8;
  float s[NSPLIT];
#pragma unroll
  for (int i = 0; i < NSPLIT; ++i) s[i] = sb[(size_t)i * NROWS + r];
  const float S = fmaxf(fmaxf(s[0], s[1]), fmaxf(s[2], s[3]));
  float a[NSPLIT], wsum = 0.f;
#pragma unroll
  for (int i = 0; i < NSPLIT; ++i) { a[i] = exp2f(s[i] - S); wsum += a[i]; }
  const float inv = 1.0f / wsum;
  float acc[8] = {};
#pragma unroll
  for (int i = 0; i < NSPLIT; ++i) {
    const float ai = a[i] * inv;
    const uint4 u = *(const uint4*)&opart[(size_t)i * NROWS * DH +
                                          (size_t)r * DH + dseg];
    const unsigned int* pu = (const unsigned int*)&u;
#pragma unroll
    for (int j = 0; j < 4; ++j) {
      acc[2 * j]     += ai * __uint_as_float(pu[j] << 16);
      acc[2 * j + 1] += ai * __uint_as_float(pu[j] & 0xffff0000u);
    }
  }
  unsigned int ow[4];
#pragma unroll
  for (int j = 0; j < 4; ++j) ow[j] = pack_bf2(acc[2 * j], acc[2 * j + 1]);
  const int bh = r >> 12, q = r & 4095;
  const int bb = bh >> 3, hh = bh & 7;
  *(uint4*)&yb[((size_t)(bb * T_SEQ + q)) * 512 + hh * DH + dseg] = *(uint4*)ow;
}

// ---------------- launch ----------------
extern "C" void kernel_launch(void* const* d_in, const int* in_sizes, int n_in,
                              void* d_out, int out_size, void* d_ws, size_t ws_size,
                              hipStream_t stream) {
  const float* x     = (const float*)d_in[0];
  const float* w_qkv = (const float*)d_in[1];
  const float* b_qkv = (const float*)d_in[2];
  const float* w_out = (const float*)d_in[3];
  const float* b_out = (const float*)d_in[4];
  float* out = (float*)d_out;

  char* p = (char*)d_ws;
  unsigned short* xb    = (unsigned short*)p; p += (size_t)8192 * 512 * 2;
  unsigned short* wqkvT = (unsigned short*)p; p += (size_t)1536 * 512 * 2;
  unsigned short* woutT = (unsigned short*)p; p += (size_t)512 * 512 * 2;
  unsigned short* qbuf  = (unsigned short*)p; p += (size_t)16 * T_SEQ * DH * 2;
  unsigned short* kbuf  = (unsigned short*)p; p += (size_t)16 * T_SEQ * DH * 2;
  unsigned short* vtbuf = (unsigned short*)p; p += (size_t)16 * T_SEQ * DH * 2;
  unsigned short* ybuf  = (unsigned short*)p; p += (size_t)8192 * 512 * 2;
  unsigned short* opart = (unsigned short*)p; p += (size_t)NSPLIT * NROWS * DH * 2;
  float*          sbuf  = (float*)p;          p += (size_t)NSPLIT * NROWS * 4;

  cvt_x_kernel<<<4096, 256, 0, stream>>>(x, xb, 8192 * 512 / 4);
  cvt_T_kernel<<<3072, 256, 0, stream>>>(w_qkv, wqkvT, 1536, 1536 * 512);
  cvt_T_kernel<<<1024, 256, 0, stream>>>(w_out, woutT, 512, 512 * 512);

  // QKV projection: M=8192, N=1536, K=512
  gemm_bt<0><<<dim3(12, 64), 256, 0, stream>>>(xb, wqkvT, b_qkv, nullptr,
                                               qbuf, kbuf, vtbuf, 512);
  // attention: 128-q superblocks, paired + 4-way split-K (1024 equal blocks)
  attn_kernel<<<dim3(16, 16, NSPLIT), 256, 0, stream>>>(qbuf, kbuf, vtbuf,
                                                        opart, sbuf);
  merge_kernel<<<NROWS / 32, 256, 0, stream>>>(opart, sbuf, ybuf);
  // output projection: M=8192, N=512, K=512
  gemm_bt<1><<<dim3(4, 64), 256, 0, stream>>>(ybuf, woutT, b_out, out,
                                              nullptr, nullptr, nullptr, 512);
}

// Round 14
// 133.624 us; speedup vs baseline: 1.2224x; 1.0334x over previous
//
#include <hip/hip_runtime.h>
#include <cstdint>
#include <cstddef>

// ---------------- types / helpers ----------------
typedef __attribute__((ext_vector_type(8)))  __bf16 bf16x8;
typedef __attribute__((ext_vector_type(4)))  float  f32x4;
typedef __attribute__((ext_vector_type(16))) float  f32x16;

#define MFMA16(a, b, c) __builtin_amdgcn_mfma_f32_16x16x32_bf16((a), (b), (c), 0, 0, 0)
#define MFMA32(a, b, c) __builtin_amdgcn_mfma_f32_32x32x16_bf16((a), (b), (c), 0, 0, 0)

#define T_SEQ 4096
#define NHEADS 8
#define DH 64
#define NROWS (2 * NHEADS * T_SEQ)   // 65536 total (bh, q) rows
#define NSPLIT 4
#define NEG_INF (-__builtin_huge_valf())
// 1/sqrt(64) * log2(e)  (softmax done in exp2 domain)
#define SCALE_Q 0.18033688011112042f

__device__ __forceinline__ unsigned short f2bf(float f) {
  unsigned int u = __float_as_uint(f);
  u += 0x7fffu + ((u >> 16) & 1u);
  return (unsigned short)(u >> 16);
}

// pack two f32 -> two bf16 in one u32 (hardware cvt_pk, RNE; lo = low half)
__device__ __forceinline__ unsigned int cvtpk(float lo, float hi) {
  unsigned int r;
  asm("v_cvt_pk_bf16_f32 %0, %1, %2" : "=v"(r) : "v"(lo), "v"(hi));
  return r;
}

// v_permlane32_swap_b32 vdst, vsrc: vdst.hi(32:63) <-> vsrc.lo(0:31)
// ((a,b) low-key-pair-first order verified on HW in R12)
__device__ __forceinline__ void swap32(unsigned int& x, unsigned int& y) {
  asm("v_permlane32_swap_b32 %0, %1" : "+v"(x), "+v"(y));
}

// pack two f32 -> two bf16 in one u32 (round-half-up; a = low half)
__device__ __forceinline__ unsigned int pack_bf2(float a, float b) {
  unsigned int au = __float_as_uint(a) + 0x8000u;
  unsigned int bu = __float_as_uint(b) + 0x8000u;
  return (au >> 16) | (bu & 0xffff0000u);
}

// async global->LDS, 16B per lane. LDS dest = uniform base + lane*16.
__device__ __forceinline__ void gload16(const unsigned short* g, unsigned short* l) {
  __builtin_amdgcn_global_load_lds(
      (const __attribute__((address_space(1))) unsigned short*)g,
      (__attribute__((address_space(3))) unsigned short*)l, 16, 0, 0);
}

// ---------------- conversion kernels ----------------
__global__ void cvt_x_kernel(const float* __restrict__ x,
                             unsigned short* __restrict__ xb, int n4) {
  int i = blockIdx.x * blockDim.x + threadIdx.x;
  if (i >= n4) return;
  float4 v = ((const float4*)x)[i];
  ushort4 o;
  o.x = f2bf(v.x); o.y = f2bf(v.y); o.z = f2bf(v.z); o.w = f2bf(v.w);
  ((ushort4*)xb)[i] = o;
}

// w [512][N] (K=512 rows) -> wT [N][512] bf16
__global__ void cvt_T_kernel(const float* __restrict__ w,
                             unsigned short* __restrict__ wT, int N, int total) {
  int i = blockIdx.x * blockDim.x + threadIdx.x;
  if (i >= total) return;
  int n = i >> 9, k = i & 511;
  wT[i] = f2bf(w[(size_t)k * N + n]);
}

// ---------------- GEMM: C = A[M,K] * BT[N,K]^T + bias ----------------
// 128x128 block tile, BK=32, 4 waves (each a 64x64 quadrant), 16x16x32 MFMA.
// m97-style staging: double-buffered LDS filled by global_load_lds dwordx4
// (4 insts per matrix per K-step), prefetch of step k+1 issued before the
// compute of step k; ONE barrier per step (compiler drains vmcnt before
// s_barrier, publishing the prefetched tile).
// EPI==0: QKV epilogue (q/k -> [B*H][T][64], V -> transposed [B*H][64][T])
// EPI==1: fp32 output [M][512] with bias
template <int EPI>
__global__ __launch_bounds__(256) void gemm_bt(
    const unsigned short* __restrict__ A,
    const unsigned short* __restrict__ BT,
    const float* __restrict__ bias,
    float* __restrict__ outf,
    unsigned short* __restrict__ oq,
    unsigned short* __restrict__ ok,
    unsigned short* __restrict__ ovT,
    int K) {
  __shared__ alignas(16) unsigned short As[2][128 * 32];
  __shared__ alignas(16) unsigned short Bs[2][128 * 32];

  const int t = threadIdx.x;
  const int lane = t & 63;
  const int w = t >> 6;
  const int wr = (w >> 1) * 64;
  const int wc = (w & 1) * 64;
  const int g = lane >> 4, c = lane & 15;
  const int row0 = blockIdx.y * 128, col0 = blockIdx.x * 128;

  // staging map: lane covers row sr = t>>2 (64-row half per inst), 16B at
  // col (t&3)*8. LDS offset = sr*32 + (t&3)*8 = w*512 + lane*8 (linear).
  const int sr = t >> 2;
  const int sc = (t & 3) * 8;
  const unsigned short* Asrc0 = A + (size_t)(row0 + sr) * K + sc;
  const unsigned short* Asrc1 = A + (size_t)(row0 + 64 + sr) * K + sc;
  const unsigned short* Bsrc0 = BT + (size_t)(col0 + sr) * K + sc;
  const unsigned short* Bsrc1 = BT + (size_t)(col0 + 64 + sr) * K + sc;

#define STAGE_G(B, K0) do {                                    \
    gload16(Asrc0 + (K0), &As[B][w * 512]);                    \
    gload16(Asrc1 + (K0), &As[B][2048 + w * 512]);             \
    gload16(Bsrc0 + (K0), &Bs[B][w * 512]);                    \
    gload16(Bsrc1 + (K0), &Bs[B][2048 + w * 512]);             \
  } while (0)

  f32x4 acc[4][4] = {};

  STAGE_G(0, 0);
  __syncthreads();
  int cur = 0;

  for (int k0 = 0; k0 < K; k0 += 32) {
    if (k0 + 32 < K) STAGE_G(cur ^ 1, k0 + 32);

    bf16x8 af[4], bfr[4];
#pragma unroll
    for (int m = 0; m < 4; ++m)
      af[m] = *(const bf16x8*)&As[cur][(wr + m * 16 + c) * 32 + g * 8];
#pragma unroll
    for (int n = 0; n < 4; ++n)
      bfr[n] = *(const bf16x8*)&Bs[cur][(wc + n * 16 + c) * 32 + g * 8];
#pragma unroll
    for (int m = 0; m < 4; ++m)
#pragma unroll
      for (int n = 0; n < 4; ++n)
        acc[m][n] = MFMA16(af[m], bfr[n], acc[m][n]);

    __syncthreads();  // publishes prefetched tile + guards buffer reuse
    cur ^= 1;
  }
#undef STAGE_G

  // epilogue. D layout: row = g*4 + i, col = c (verified m89/m91 mapping)
#pragma unroll
  for (int m = 0; m < 4; ++m) {
#pragma unroll
    for (int n = 0; n < 4; ++n) {
      const int col = col0 + wc + n * 16 + c;
      const float bv = bias[col];
      if constexpr (EPI == 0) {
        const int which = col >> 9;          // wave-uniform (depends on block,n)
        const int h = (col >> 6) & 7;
        const int dh = col & 63;
        const int r0 = row0 + wr + m * 16 + g * 4;
        const int bb = r0 >> 12;             // r0 / T_SEQ (4 rows never cross)
        const int tt0 = r0 & 4095;
        if (which == 2) {
          // V transposed: vT[(bb*H + h)*64 + dh][tt0..tt0+3] -- contiguous
          ushort4 pk;
          pk.x = f2bf(acc[m][n][0] + bv);
          pk.y = f2bf(acc[m][n][1] + bv);
          pk.z = f2bf(acc[m][n][2] + bv);
          pk.w = f2bf(acc[m][n][3] + bv);
          *(ushort4*)&ovT[((size_t)((bb * NHEADS + h) * DH + dh)) * T_SEQ + tt0] = pk;
        } else {
          unsigned short* dst = (which == 0) ? oq : ok;
          const float sc2 = (which == 0) ? SCALE_Q : 1.0f;
#pragma unroll
          for (int i = 0; i < 4; ++i) {
            const size_t idx =
                ((size_t)((bb * NHEADS + h) * T_SEQ + tt0 + i)) * DH + dh;
            dst[idx] = f2bf((acc[m][n][i] + bv) * sc2);
          }
        }
      } else {
#pragma unroll
        for (int i = 0; i < 4; ++i) {
          const int row = row0 + wr + m * 16 + g * 4 + i;
          outf[(size_t)row * 512 + col] = acc[m][n][i] + bv;
        }
      }
    }
  }
}

// ---------------- flash attention (causal, 4-way split-K, 32x32 MFMA) -----
// grid (B*H, 16, 4). Block (bh, y, hv) runs two passes over 128-row
// q-superblocks (sb = y, 31-y), key-tile QUARTER hv of each:
// [ (ntp*hv)>>2, (ntp*(hv+1))>>2 ). Pairing keeps every block at ~16-17
// tiles; 1024 equal blocks = 4 blocks/CU (128 KB LDS, 64 VGPR) = 4 waves/
// SIMD. Per wave: 32 q-rows via 32x32x16 MFMA, both products swapped; P
// stays in registers via cvt_pk + permlane32_swap (T12). LDS = K,V dbuf.
__global__ __launch_bounds__(256, 4) void attn_kernel(
    const unsigned short* __restrict__ qb,
    const unsigned short* __restrict__ kb,
    const unsigned short* __restrict__ vtb,
    unsigned short* __restrict__ opart,   // NSPLIT partials, contiguous
    float* __restrict__ sb) {
  const int bh = blockIdx.x;
  const int y = blockIdx.y;
  const int hv = blockIdx.z;
  const int w = threadIdx.x >> 6;
  const int lane = threadIdx.x & 63;
  const int q32 = lane & 31;          // lane-local q row (and d row for acc)
  const int h = lane >> 5;            // half index
  const int swb = (lane & 7) << 4;    // read-side xor (bytes), row&7 == lane&7

  // K tile: rows = key (64), cols = d (64, 128B). V tile: rows = d, cols = t.
  __shared__ alignas(16) unsigned short Ks[2][64 * 64];
  __shared__ alignas(16) unsigned short Vs[2][64 * 64];

  const unsigned short* Qp  = qb + (size_t)bh * T_SEQ * DH;
  const unsigned short* Kp  = kb + (size_t)bh * T_SEQ * DH;
  const unsigned short* VTp = vtb + (size_t)bh * DH * T_SEQ;

  unsigned short* obh = opart + (size_t)hv * NROWS * DH;
  float* sbh = sb + (size_t)hv * NROWS + (size_t)bh * T_SEQ;

  // staging: wave w stages LDS rows 16w..16w+15 of both tiles (2 gloads each).
  // source column pre-swizzled: row r keeps byte-col cb at cb ^ ((r&7)<<4);
  // gload instr writes rows q*8+l8 linearly, so swizzle = 8*(lc ^ l8) elems.
  const int l8 = lane >> 3, lc = lane & 7;
  const int swzE = 8 * (lc ^ l8);
  const unsigned short* Ksrc0 = Kp + (size_t)(16 * w + l8) * DH + swzE;
  const unsigned short* Ksrc1 = Kp + (size_t)(16 * w + 8 + l8) * DH + swzE;
  const unsigned short* Vsrc0 = VTp + (size_t)(16 * w + l8) * T_SEQ + swzE;
  const unsigned short* Vsrc1 = VTp + (size_t)(16 * w + 8 + l8) * T_SEQ + swzE;

#define STAGE(B, J0) do {                                              \
    gload16(Ksrc0 + (size_t)(J0) * DH, &Ks[B][(2 * w) * 512]);         \
    gload16(Ksrc1 + (size_t)(J0) * DH, &Ks[B][(2 * w + 1) * 512]);     \
    gload16(Vsrc0 + (J0), &Vs[B][(2 * w) * 512]);                      \
    gload16(Vsrc1 + (J0), &Vs[B][(2 * w + 1) * 512]);                  \
  } while (0)

  for (int pass = 0; pass < 2; ++pass) {
    const int sbk = pass ? (31 - y) : y;      // q-superblock (128 rows)
    const int qw = sbk * 128 + w * 32;        // this wave's 32 q-rows
    const int ntp = 2 * sbk + 2;              // tiles needed by wave 3
    const int t0 = (ntp * hv) >> 2;           // quarter range [t0, t1)
    const int t1 = (ntp * (hv + 1)) >> 2;
    const int tlast = (qw + 31) >> 6;         // this wave's diagonal tile

    // Q fragments (B-operand of swapped QK): col=q=lane&31, k=16d+8h+e
    bf16x8 qf[4];
#pragma unroll
    for (int d = 0; d < 4; ++d)
      qf[d] = *(const bf16x8*)&Qp[(size_t)(qw + q32) * DH + 16 * d + 8 * h];

    f32x16 acc0 = {}, acc1 = {};
    float mi = NEG_INF;   // running row-max for q = qw + q32 (exp2 domain)
    float li = 0.f;       // running row-sum

    STAGE(0, t0 * 64);
    __syncthreads();  // compiler drains vmcnt(0) before s_barrier
    int cur = 0;

    for (int t = t0; t < t1; ++t) {
      if (t + 1 < t1) STAGE(cur ^ 1, (t + 1) * 64);

      if (t <= tlast) {  // wave-uniform; no barriers inside
        const char* Kb = (const char*)&Ks[cur][0];
        const char* Vb = (const char*)&Vs[cur][0];

        // S = K.Q^T (swapped): s{0,1}[r] = S[key=ks*32+(r&3)+8(r>>2)+4h][q]
        f32x16 s0 = {}, s1 = {};
#pragma unroll
        for (int d = 0; d < 4; ++d) {
          bf16x8 kf0 = *(const bf16x8*)(Kb + q32 * 128 +
                                        ((32 * d + 16 * h) ^ swb));
          bf16x8 kf1 = *(const bf16x8*)(Kb + (32 + q32) * 128 +
                                        ((32 * d + 16 * h) ^ swb));
          s0 = MFMA32(kf0, qf[d], s0);
          s1 = MFMA32(kf1, qf[d], s1);
        }

        if (t == tlast) {  // diagonal tile: causal mask (key > q)
          const int qq = qw + q32;
          const int kb0 = t * 64 + 4 * h;
#pragma unroll
          for (int r = 0; r < 16; ++r) {
            const int ko = kb0 + (r & 3) + 8 * (r >> 2);
            if (ko > qq) s0[r] = NEG_INF;
            if (ko + 32 > qq) s1[r] = NEG_INF;
          }
        }

        // row max: 31-op local tree + one cross-half shuffle
        float mv[8];
#pragma unroll
        for (int i = 0; i < 8; ++i)
          mv[i] = fmaxf(fmaxf(s0[2 * i], s0[2 * i + 1]),
                        fmaxf(s1[2 * i], s1[2 * i + 1]));
        float mloc = fmaxf(fmaxf(fmaxf(mv[0], mv[1]), fmaxf(mv[2], mv[3])),
                           fmaxf(fmaxf(mv[4], mv[5]), fmaxf(mv[6], mv[7])));
        mloc = fmaxf(mloc, __shfl_xor(mloc, 32));

        // defer-max: only rescale when some row grew past THR=8
        if (__ballot(mloc > mi + 8.0f) != 0ull) {
          const float mn = fmaxf(mi, mloc);
          const float scq = exp2f(mi - mn);
          mi = mn;
          li *= scq;
#pragma unroll
          for (int r = 0; r < 16; ++r) { acc0[r] *= scq; acc1[r] *= scq; }
        }

        // per 16-key step: exp2 -> cvt_pk -> permlane swap -> PV MFMA
        float ls = 0.f;
#pragma unroll
        for (int kk = 0; kk < 4; ++kk) {
          float pv[8];
#pragma unroll
          for (int e = 0; e < 8; ++e) {
            const float sv = (kk < 2) ? s0[(kk & 1) * 8 + e]
                                      : s1[(kk & 1) * 8 + e];
            pv[e] = exp2f(sv - mi);
          }
          ls += ((pv[0] + pv[1]) + (pv[2] + pv[3])) +
                ((pv[4] + pv[5]) + (pv[6] + pv[7]));
          // own pairs: a0=keys 4h+{0,1}, a1=4h+{2,3}, b0=8+4h+{0,1}, b1=...
          unsigned int a0 = cvtpk(pv[0], pv[1]);
          unsigned int a1 = cvtpk(pv[2], pv[3]);
          unsigned int b0 = cvtpk(pv[4], pv[5]);
          unsigned int b1 = cvtpk(pv[6], pv[7]);
          // swap32(a,b): a.hi <-> b.lo (low-key pair FIRST, HW-verified R12)
          swap32(a0, b0);
          swap32(a1, b1);
          union { unsigned int u[4]; bf16x8 v; } pf;
          pf.u[0] = a0; pf.u[1] = a1; pf.u[2] = b0; pf.u[3] = b1;

          bf16x8 vf0 = *(const bf16x8*)(Vb + q32 * 128 +
                                        ((32 * kk + 16 * h) ^ swb));
          bf16x8 vf1 = *(const bf16x8*)(Vb + (32 + q32) * 128 +
                                        ((32 * kk + 16 * h) ^ swb));
          acc0 = MFMA32(vf0, pf.v, acc0);
          acc1 = MFMA32(vf1, pf.v, acc1);
        }
        ls += __shfl_xor(ls, 32);
        li += ls;
      }

      // barrier: publishes prefetched tile (vmcnt drain) + buf-reuse guard
      __syncthreads();
      cur ^= 1;
    }

    // partial epilogue: o_norm (bf16) + s = mi + log2(li) per q-row.
    // acc: lane q = lane&31, d = (r&3)+8(r>>2)+4h (+32 for acc1)
    if (lane < 32) sbh[qw + lane] = (li > 0.f) ? (mi + log2f(li)) : NEG_INF;
    const float inv = (li > 0.f) ? 1.0f / li : 0.f;
    const size_t base = ((size_t)bh * T_SEQ + qw + q32) * DH;
#pragma unroll
    for (int dt = 0; dt < 2; ++dt) {
#pragma unroll
      for (int p4 = 0; p4 < 4; ++p4) {
        const float v0 = (dt ? acc1[4 * p4 + 0] : acc0[4 * p4 + 0]) * inv;
        const float v1 = (dt ? acc1[4 * p4 + 1] : acc0[4 * p4 + 1]) * inv;
        const float v2 = (dt ? acc1[4 * p4 + 2] : acc0[4 * p4 + 2]) * inv;
        const float v3 = (dt ? acc1[4 * p4 + 3] : acc0[4 * p4 + 3]) * inv;
        const int d0 = 32 * dt + 8 * p4 + 4 * h;
        *(unsigned int*)&obh[base + d0]     = cvtpk(v0, v1);
        *(unsigned int*)&obh[base + d0 + 2] = cvtpk(v2, v3);
      }
    }
  }
#undef STAGE
}

// ---------------- split-K merge (4 partials) ----------------
// y[(b*T+q)*512 + h*64 + d] = sum_i w_i * o_i, w_i = 2^(s_i - max) normalized.
// 256 threads = 32 rows x 8 dim-segments (8 bf16 = 16B each).
__global__ __launch_bounds__(256) void merge_kernel(
    const unsigned short* __restrict__ opart,
    const float* __restrict__ sb,
    unsigned short* __restrict__ yb) {
  const int t = threadIdx.x;
  const int r = blockIdx.x * 32 + (t >> 3);   // global (bh,q) row, 0..65535
  const int dseg = (t & 7) * 8;
  float s[NSPLIT];
#pragma unroll
  for (int i = 0; i < NSPLIT; ++i) s[i] = sb[(size_t)i * NROWS + r];
  const float S = fmaxf(fmaxf(s[0], s[1]), fmaxf(s[2], s[3]));
  float a[NSPLIT], wsum = 0.f;
#pragma unroll
  for (int i = 0; i < NSPLIT; ++i) { a[i] = exp2f(s[i] - S); wsum += a[i]; }
  const float inv = 1.0f / wsum;
  float acc[8] = {};
#pragma unroll
  for (int i = 0; i < NSPLIT; ++i) {
    const float ai = a[i] * inv;
    const uint4 u = *(const uint4*)&opart[(size_t)i * NROWS * DH +
                                          (size_t)r * DH + dseg];
    const unsigned int* pu = (const unsigned int*)&u;
#pragma unroll
    for (int j = 0; j < 4; ++j) {
      acc[2 * j]     += ai * __uint_as_float(pu[j] << 16);
      acc[2 * j + 1] += ai * __uint_as_float(pu[j] & 0xffff0000u);
    }
  }
  unsigned int ow[4];
#pragma unroll
  for (int j = 0; j < 4; ++j) ow[j] = pack_bf2(acc[2 * j], acc[2 * j + 1]);
  const int bh = r >> 12, q = r & 4095;
  const int bb = bh >> 3, hh = bh & 7;
  *(uint4*)&yb[((size_t)(bb * T_SEQ + q)) * 512 + hh * DH + dseg] = *(uint4*)ow;
}

// ---------------- launch ----------------
extern "C" void kernel_launch(void* const* d_in, const int* in_sizes, int n_in,
                              void* d_out, int out_size, void* d_ws, size_t ws_size,
                              hipStream_t stream) {
  const float* x     = (const float*)d_in[0];
  const float* w_qkv = (const float*)d_in[1];
  const float* b_qkv = (const float*)d_in[2];
  const float* w_out = (const float*)d_in[3];
  const float* b_out = (const float*)d_in[4];
  float* out = (float*)d_out;

  char* p = (char*)d_ws;
  unsigned short* xb    = (unsigned short*)p; p += (size_t)8192 * 512 * 2;
  unsigned short* wqkvT = (unsigned short*)p; p += (size_t)1536 * 512 * 2;
  unsigned short* woutT = (unsigned short*)p; p += (size_t)512 * 512 * 2;
  unsigned short* qbuf  = (unsigned short*)p; p += (size_t)16 * T_SEQ * DH * 2;
  unsigned short* kbuf  = (unsigned short*)p; p += (size_t)16 * T_SEQ * DH * 2;
  unsigned short* vtbuf = (unsigned short*)p; p += (size_t)16 * T_SEQ * DH * 2;
  unsigned short* ybuf  = (unsigned short*)p; p += (size_t)8192 * 512 * 2;
  unsigned short* opart = (unsigned short*)p; p += (size_t)NSPLIT * NROWS * DH * 2;
  float*          sbuf  = (float*)p;          p += (size_t)NSPLIT * NROWS * 4;

  cvt_x_kernel<<<4096, 256, 0, stream>>>(x, xb, 8192 * 512 / 4);
  cvt_T_kernel<<<3072, 256, 0, stream>>>(w_qkv, wqkvT, 1536, 1536 * 512);
  cvt_T_kernel<<<1024, 256, 0, stream>>>(w_out, woutT, 512, 512 * 512);

  // QKV projection: M=8192, N=1536, K=512
  gemm_bt<0><<<dim3(12, 64), 256, 0, stream>>>(xb, wqkvT, b_qkv, nullptr,
                                               qbuf, kbuf, vtbuf, 512);
  // attention: 128-q superblocks, paired + 4-way split-K (1024 equal blocks)
  attn_kernel<<<dim3(16, 16, NSPLIT), 256, 0, stream>>>(qbuf, kbuf, vtbuf,
                                                        opart, sbuf);
  merge_kernel<<<NROWS / 32, 256, 0, stream>>>(opart, sbuf, ybuf);
  // output projection: M=8192, N=512, K=512
  gemm_bt<1><<<dim3(4, 64), 256, 0, stream>>>(ybuf, woutT, b_out, out,
                                              nullptr, nullptr, nullptr, 512);
}